// Round 3
// baseline (243.719 us; speedup 1.0000x reference)
//
#include <hip/hip_runtime.h>

#define ALPHA 0.90483741803595957f

// ---------------------------------------------------------------------------
// K0: fold avgpool into conv kernels.
// W1eff[oc][ch][u][v] (4x2x8x8): conv1 5x5 pad2 + pool4  => 8x8 stride-4 conv
// W2eff[oc][ch][u][v] (8x4x4x4): conv2 3x3 pad1 + pool2  => 4x4 stride-2 conv
// ---------------------------------------------------------------------------
__global__ void prep_weights(const float* __restrict__ w1, const float* __restrict__ w2,
                             float* __restrict__ w1e, float* __restrict__ w2e) {
    int idx = blockIdx.x * 256 + threadIdx.x;
    if (idx < 512) {
        int v = idx & 7, u = (idx >> 3) & 7, ch = (idx >> 6) & 1, oc = idx >> 7;
        float s = 0.f;
        for (int a = 0; a < 5; ++a) {
            int i = u - a; if (i < 0 || i > 3) continue;
            for (int b = 0; b < 5; ++b) {
                int j = v - b; if (j < 0 || j > 3) continue;
                s += w1[((oc * 2 + ch) * 5 + a) * 5 + b];
            }
        }
        w1e[idx] = s * (1.f / 16.f);
    } else if (idx < 1024) {
        int k = idx - 512;
        int v = k & 3, u = (k >> 2) & 3, ch = (k >> 4) & 3, oc = k >> 6;
        float s = 0.f;
        for (int a = 0; a < 3; ++a) {
            int i = u - a; if (i < 0 || i > 1) continue;
            for (int b = 0; b < 3; ++b) {
                int j = v - b; if (j < 0 || j > 1) continue;
                s += w2[((oc * 4 + ch) * 3 + a) * 3 + b];
            }
        }
        w2e[k] = s * 0.25f;
    }
}

// ---------------------------------------------------------------------------
// K1 v2: conv1 + pool4 (8x8/stride-4 effective kernel).
// 2 images per block (20.7 KB LDS -> ~7 blocks/CU). Wave w: image w>>1,
// oc-pair w&1. Each lane: one (p,q), 2 output channels, 256 FMAs, 256 weight
// s_loads (half of v1 -> shorter scalar-load chain).
// ---------------------------------------------------------------------------
__global__ __launch_bounds__(256) void conv1_pool(const float* __restrict__ x,
                                                  const float* __restrict__ w1e,
                                                  float* __restrict__ y1) {
    __shared__ __align__(16) float tile[2][2][36][36];  // 20736 B
    int tid = threadIdx.x;

    float4* t4 = (float4*)&tile[0][0][0][0];
    #pragma unroll
    for (int k = 0; k < 6; ++k) {
        int i = tid + k * 256;
        if (i < 1296) t4[i] = make_float4(0.f, 0.f, 0.f, 0.f);
    }
    __syncthreads();

    long gi0 = (long)blockIdx.x * 2;
    int simg = tid >> 7, soff = tid & 127;       // 128 threads stage each image
    const float* src = x + (gi0 + simg) * 2048;
    #pragma unroll
    for (int k = 0; k < 4; ++k) {
        int e = k * 512 + soff * 4;
        float4 d = *(const float4*)(src + e);
        int ch = e >> 10, rem = e & 1023, r = rem >> 5, c = rem & 31;
        float* dst = &tile[simg][ch][r + 2][c + 2];   // 8B-aligned (c%4==0 -> c+2 even)
        *(float2*)dst = make_float2(d.x, d.y);
        *(float2*)(dst + 2) = make_float2(d.z, d.w);
    }
    __syncthreads();

    int w = tid >> 6, im = w >> 1, ocp = w & 1;
    int pos = tid & 63, p = pos >> 3, q = pos & 7;
    float acc0 = 0.f, acc1 = 0.f;
    const float* wb = w1e + ocp * 256;           // oc0 = 2*ocp
    #pragma unroll
    for (int ch = 0; ch < 2; ++ch) {
        #pragma unroll
        for (int r = 0; r < 8; ++r) {
            const float* row = &tile[im][ch][4 * p + r][4 * q];  // 16B aligned
            float4 a = *(const float4*)row;
            float4 b = *(const float4*)(row + 4);
            const float* w0 = wb + ch * 64 + r * 8;   // uniform -> s_load
            const float* w1 = w0 + 128;
            acc0 += w0[0] * a.x + w0[1] * a.y + w0[2] * a.z + w0[3] * a.w
                  + w0[4] * b.x + w0[5] * b.y + w0[6] * b.z + w0[7] * b.w;
            acc1 += w1[0] * a.x + w1[1] * a.y + w1[2] * a.z + w1[3] * a.w
                  + w1[4] * b.x + w1[5] * b.y + w1[6] * b.z + w1[7] * b.w;
        }
    }
    // f = oc*64 + pos; oc = 2*ocp, 2*ocp+1
    float* dst = y1 + (gi0 + im) * 256 + ocp * 128 + pos;
    dst[0] = acc0; dst[64] = acc1;
}

// ---------------------------------------------------------------------------
// K2 v2: FUSED scan1 + conv2+pool2 + scan2 + linear. ONE WAVE per block
// (one block per b) -> no s_barrier cost, lockstep wave-synchronous LDS.
// Per t: each lane does 4 stage-1 LIF chains (f = lane+64k), writes spikes to
// padded LDS tile; then computes 2 conv2 outputs (g=lane, g=lane+64) with
// register-resident effective weights; stage-2 LIF; s2 -> LDS[t].
// Epilogue: 128->2 linear for all t in parallel (lane -> t, t+64).
// ---------------------------------------------------------------------------
__global__ __launch_bounds__(64) void fused_rest(const float* __restrict__ y1,
                                                 const float* __restrict__ w2e,
                                                 const float* __restrict__ lw,
                                                 float* __restrict__ out) {
    __shared__ __align__(16) float spk[4][10][12];    // padded spike tile
    __shared__ __align__(16) float s2all[100][132];   // stride 132 -> conflict-free b128
    __shared__ __align__(16) float lwl[256];
    int lane = threadIdx.x;
    int b = blockIdx.x;

    for (int i = lane; i < 480; i += 64) ((float*)spk)[i] = 0.f;
    ((float4*)lwl)[lane] = ((const float4*)lw)[lane];   // 256 floats

    // conv2 effective weights for oc = lane>>4 and oc+4 (registers)
    float wr0[64], wr1[64];
    {
        const float4* ws0 = (const float4*)(w2e + (lane >> 4) * 64);
        const float4* ws1 = (const float4*)(w2e + ((lane >> 4) + 4) * 64);
        #pragma unroll
        for (int k = 0; k < 16; ++k) {
            float4 a = ws0[k];
            wr0[4 * k] = a.x; wr0[4 * k + 1] = a.y; wr0[4 * k + 2] = a.z; wr0[4 * k + 3] = a.w;
            float4 c = ws1[k];
            wr1[4 * k] = c.x; wr1[4 * k + 1] = c.y; wr1[4 * k + 2] = c.z; wr1[4 * k + 3] = c.w;
        }
    }

    int r1 = (lane >> 3) & 7, c1 = lane & 7;    // stage-1 spatial (per ch)
    int p = (lane >> 2) & 3, q = lane & 3;      // stage-2 spatial
    const float* yp = y1 + (long)b * 25600 + lane;

    float v1a[4] = {0.f, 0.f, 0.f, 0.f}, v1b[4] = {0.f, 0.f, 0.f, 0.f};
    float v2a0 = 0.f, v2b0 = 0.f, v2a1 = 0.f, v2b1 = 0.f;
    float xt[4];
    #pragma unroll
    for (int k = 0; k < 4; ++k) xt[k] = yp[k * 64];
    __syncthreads();

    for (int t = 0; t < 100; ++t) {
        float xn[4];
        if (t < 99) {
            const float* ypn = yp + (t + 1) * 256;
            #pragma unroll
            for (int k = 0; k < 4; ++k) xn[k] = ypn[k * 64];   // prefetch
        } else {
            #pragma unroll
            for (int k = 0; k < 4; ++k) xn[k] = 0.f;
        }
        #pragma unroll
        for (int k = 0; k < 4; ++k) {
            v1a[k] = ALPHA * v1a[k] + xt[k];
            v1b[k] = ALPHA * v1b[k] + v1a[k];
            float s = (v1b[k] >= 1.f) ? 1.f : 0.f;
            v1b[k] -= s;
            spk[k][r1 + 1][c1 + 1] = s;
            xt[k] = xn[k];
        }
        __syncthreads();   // 1 wave: compiles to waitcnt-level sync

        float acc0 = 0.f, acc1 = 0.f;
        #pragma unroll
        for (int cc = 0; cc < 4; ++cc) {
            #pragma unroll
            for (int rr = 0; rr < 4; ++rr) {
                const float* rowp = &spk[cc][2 * p + rr][2 * q];  // 8B aligned
                float2 a = *(const float2*)rowp;
                float2 bb = *(const float2*)(rowp + 2);
                int wx = cc * 16 + rr * 4;
                acc0 += wr0[wx] * a.x + wr0[wx + 1] * a.y + wr0[wx + 2] * bb.x + wr0[wx + 3] * bb.y;
                acc1 += wr1[wx] * a.x + wr1[wx + 1] * a.y + wr1[wx + 2] * bb.x + wr1[wx + 3] * bb.y;
            }
        }
        v2a0 = ALPHA * v2a0 + acc0; v2b0 = ALPHA * v2b0 + v2a0;
        float s0 = (v2b0 >= 1.f) ? 1.f : 0.f; v2b0 -= s0;
        v2a1 = ALPHA * v2a1 + acc1; v2b1 = ALPHA * v2b1 + v2a1;
        float s1 = (v2b1 >= 1.f) ? 1.f : 0.f; v2b1 -= s1;
        s2all[t][lane] = s0;
        s2all[t][lane + 64] = s1;
        __syncthreads();
    }

    // Epilogue: out[t][o] = sum_f s2all[t][f] * lw[o][f]; lane -> t=lane, t=lane+64
    int tb = lane + 64;
    const float4* sa = (const float4*)&s2all[lane][0];
    const float4* sb = (const float4*)&s2all[(tb < 100) ? tb : 0][0];
    const float4* lw4 = (const float4*)lwl;
    float o00 = 0.f, o01 = 0.f, o10 = 0.f, o11 = 0.f;
    #pragma unroll
    for (int k = 0; k < 32; ++k) {
        float4 w0 = lw4[k], w1 = lw4[32 + k];
        float4 A = sa[k], B = sb[k];
        o00 += A.x * w0.x + A.y * w0.y + A.z * w0.z + A.w * w0.w;
        o01 += A.x * w1.x + A.y * w1.y + A.z * w1.z + A.w * w1.w;
        o10 += B.x * w0.x + B.y * w0.y + B.z * w0.z + B.w * w0.w;
        o11 += B.x * w1.x + B.y * w1.y + B.z * w1.z + B.w * w1.w;
    }
    float* op = out + (long)b * 200;
    op[lane * 2] = o00;
    op[lane * 2 + 1] = o01;
    if (tb < 100) {
        op[tb * 2] = o10;
        op[tb * 2 + 1] = o11;
    }
}

extern "C" void kernel_launch(void* const* d_in, const int* in_sizes, int n_in,
                              void* d_out, int out_size, void* d_ws, size_t ws_size,
                              hipStream_t stream) {
    const float* x  = (const float*)d_in[0];   // [128,100,2,32,32]
    const float* w1 = (const float*)d_in[1];   // [4,2,5,5]
    const float* w2 = (const float*)d_in[2];   // [8,4,3,3]
    const float* lw = (const float*)d_in[3];   // [2,128]
    float* out = (float*)d_out;                // [128,100,2]

    float* ws  = (float*)d_ws;
    float* w1e = ws;                 // 512 floats
    float* w2e = ws + 512;           // 512 floats
    float* y1  = ws + 1024;          // 12800*256 floats = 13.1 MB

    prep_weights<<<4, 256, 0, stream>>>(w1, w2, w1e, w2e);
    conv1_pool<<<6400, 256, 0, stream>>>(x, w1e, y1);
    fused_rest<<<128, 64, 0, stream>>>(y1, w2e, lw, out);
}

// Round 4
// 218.078 us; speedup vs baseline: 1.1176x; 1.1176x over previous
//
#include <hip/hip_runtime.h>

#define ALPHA 0.90483741803595957f

// ---------------------------------------------------------------------------
// K0: fold avgpool into conv kernels.
// W1eff[oc][ch][u][v] (4x2x8x8): conv1 5x5 pad2 + pool4  => 8x8 stride-4 conv
// W2eff[oc][ch][u][v] (8x4x4x4): conv2 3x3 pad1 + pool2  => 4x4 stride-2 conv
// ---------------------------------------------------------------------------
__global__ void prep_weights(const float* __restrict__ w1, const float* __restrict__ w2,
                             float* __restrict__ w1e, float* __restrict__ w2e) {
    int idx = blockIdx.x * 256 + threadIdx.x;
    if (idx < 512) {
        int v = idx & 7, u = (idx >> 3) & 7, ch = (idx >> 6) & 1, oc = idx >> 7;
        float s = 0.f;
        for (int a = 0; a < 5; ++a) {
            int i = u - a; if (i < 0 || i > 3) continue;
            for (int b = 0; b < 5; ++b) {
                int j = v - b; if (j < 0 || j > 3) continue;
                s += w1[((oc * 2 + ch) * 5 + a) * 5 + b];
            }
        }
        w1e[idx] = s * (1.f / 16.f);
    } else if (idx < 1024) {
        int k = idx - 512;
        int v = k & 3, u = (k >> 2) & 3, ch = (k >> 4) & 3, oc = k >> 6;
        float s = 0.f;
        for (int a = 0; a < 3; ++a) {
            int i = u - a; if (i < 0 || i > 1) continue;
            for (int b = 0; b < 3; ++b) {
                int j = v - b; if (j < 0 || j > 1) continue;
                s += w2[((oc * 4 + ch) * 3 + a) * 3 + b];
            }
        }
        w2e[k] = s * 0.25f;
    }
}

// ---------------------------------------------------------------------------
// K1 v3: conv1 + pool4 (8x8/stride-4 effective kernel).
// 4 images per 256-thread block; wave w stages AND computes image w (no
// inter-wave dependency after the zero-init barrier -> single barrier).
// Weights live in LDS, re-laid-out [ch][r][oc][8] so each (ch,r) step is
// 8 wave-uniform ds_read_b128 broadcasts (no s_load chain, no SGPR pressure).
// Tile rows padded to 40 floats: conv b128 reads hit the 8-cycle bank floor.
// ---------------------------------------------------------------------------
__global__ __launch_bounds__(256) void conv1_pool(const float* __restrict__ x,
                                                  const float* __restrict__ w1e,
                                                  float* __restrict__ y1) {
    __shared__ __align__(16) float tile[4][2][36][40];  // 46080 B
    __shared__ __align__(16) float wlds[512];           // [ch][r][oc][8]
    int tid = threadIdx.x;

    // zero full tile (borders must be 0; interior gets overwritten)
    float4* t4 = (float4*)&tile[0][0][0][0];
    #pragma unroll
    for (int k = 0; k < 12; ++k) {
        int i = tid + k * 256;
        if (i < 2880) t4[i] = make_float4(0.f, 0.f, 0.f, 0.f);
    }
    // weights -> LDS with (ch,r)-major relayout
    for (int j = tid; j < 512; j += 256) {
        int oc = j >> 7, ch = (j >> 6) & 1, r = (j >> 3) & 7, c = j & 7;
        wlds[((ch * 8 + r) * 4 + oc) * 8 + c] = w1e[j];
    }
    __syncthreads();

    int w = tid >> 6, lane = tid & 63;
    long gi = (long)blockIdx.x * 4 + w;      // bt index < 12800
    const float* src = x + gi * 2048;
    #pragma unroll
    for (int k = 0; k < 8; ++k) {
        int e = k * 256 + lane * 4;          // coalesced 1KB per inst
        float4 d = *(const float4*)(src + e);
        int ch = e >> 10, rem = e & 1023, r = rem >> 5, c = rem & 31;
        float* dst = &tile[w][ch][r + 2][c + 2];   // 8B-aligned
        *(float2*)dst = make_float2(d.x, d.y);
        *(float2*)(dst + 2) = make_float2(d.z, d.w);
    }
    // same-wave LDS ops are in-order: compute below safely sees our writes

    int p = lane >> 3, q = lane & 7;
    float acc0 = 0.f, acc1 = 0.f, acc2 = 0.f, acc3 = 0.f;
    #pragma unroll
    for (int ch = 0; ch < 2; ++ch) {
        #pragma unroll
        for (int r = 0; r < 8; ++r) {
            const float* row = &tile[w][ch][4 * p + r][4 * q];   // 16B aligned
            float4 a = *(const float4*)row;
            float4 b = *(const float4*)(row + 4);
            const float* wr = &wlds[(ch * 8 + r) * 32];          // wave-uniform
            float4 wa, wb;
            wa = *(const float4*)(wr + 0);  wb = *(const float4*)(wr + 4);
            acc0 += wa.x * a.x + wa.y * a.y + wa.z * a.z + wa.w * a.w
                  + wb.x * b.x + wb.y * b.y + wb.z * b.z + wb.w * b.w;
            wa = *(const float4*)(wr + 8);  wb = *(const float4*)(wr + 12);
            acc1 += wa.x * a.x + wa.y * a.y + wa.z * a.z + wa.w * a.w
                  + wb.x * b.x + wb.y * b.y + wb.z * b.z + wb.w * b.w;
            wa = *(const float4*)(wr + 16); wb = *(const float4*)(wr + 20);
            acc2 += wa.x * a.x + wa.y * a.y + wa.z * a.z + wa.w * a.w
                  + wb.x * b.x + wb.y * b.y + wb.z * b.z + wb.w * b.w;
            wa = *(const float4*)(wr + 24); wb = *(const float4*)(wr + 28);
            acc3 += wa.x * a.x + wa.y * a.y + wa.z * a.z + wa.w * a.w
                  + wb.x * b.x + wb.y * b.y + wb.z * b.z + wb.w * b.w;
        }
    }
    float* dst = y1 + gi * 256 + lane;   // f = oc*64 + p*8 + q
    dst[0] = acc0; dst[64] = acc1; dst[128] = acc2; dst[192] = acc3;
}

// ---------------------------------------------------------------------------
// K2 v3: FUSED scan1 + conv2+pool2 + scan2 + linear. 128 threads (2 waves)
// per block, one block per b. One conv2 output per thread; the 64 effective
// weights are 16 NAMED float4 SSA values (cannot be indexed-array spilled).
// __launch_bounds__(128,1) lifts the VGPR budget. conv2 accumulation split
// into 4 partials to shorten the serial FMA chain.
// ---------------------------------------------------------------------------
__global__ __launch_bounds__(128, 1) void fused_rest(const float* __restrict__ y1,
                                                     const float* __restrict__ w2e,
                                                     const float* __restrict__ lw,
                                                     float* __restrict__ out) {
    __shared__ __align__(16) float spk[4][10][12];    // padded spike tile
    __shared__ __align__(16) float s2all[100][132];   // stride 132: conflict-free
    __shared__ __align__(16) float lwl[256];
    int tid = threadIdx.x;
    int b = blockIdx.x;

    for (int i = tid; i < 480; i += 128) ((float*)spk)[i] = 0.f;
    ((float2*)lwl)[tid] = ((const float2*)lw)[tid];

    // conv2 weights for this thread's oc: 16 named float4s -> stay in VGPRs
    int oc = tid >> 4, p = (tid >> 2) & 3, q = tid & 3;
    const float4* wp = (const float4*)(w2e + oc * 64);
    float4 w00 = wp[0],  w01 = wp[1],  w02 = wp[2],  w03 = wp[3];
    float4 w04 = wp[4],  w05 = wp[5],  w06 = wp[6],  w07 = wp[7];
    float4 w08 = wp[8],  w09 = wp[9],  w10 = wp[10], w11 = wp[11];
    float4 w12 = wp[12], w13 = wp[13], w14 = wp[14], w15 = wp[15];

    // stage-1: this thread owns features f0 = tid (ch 0/1) and f1 = tid+128
    int ch1 = tid >> 6, r1 = (tid >> 3) & 7, c1 = tid & 7;
    const float* yp = y1 + (long)b * 25600 + tid;
    float v1a0 = 0.f, v1b0 = 0.f, v1a1 = 0.f, v1b1 = 0.f;
    float v2a = 0.f, v2b = 0.f;
    float xt0 = yp[0], xt1 = yp[128];
    __syncthreads();

#define C2(cc, rr, W, P) { const float* rowp = &spk[cc][2 * p + (rr)][2 * q];      \
        float2 a_ = *(const float2*)rowp; float2 b_ = *(const float2*)(rowp + 2);  \
        P += W.x * a_.x + W.y * a_.y + W.z * b_.x + W.w * b_.y; }

    for (int t = 0; t < 100; ++t) {
        float xn0 = 0.f, xn1 = 0.f;
        if (t < 99) {                        // prefetch next timestep early
            const float* ypn = yp + (t + 1) * 256;
            xn0 = ypn[0]; xn1 = ypn[128];
        }
        // stage-1 exp_leak + LIF (2 chains)
        v1a0 = ALPHA * v1a0 + xt0; v1b0 = ALPHA * v1b0 + v1a0;
        float s0 = (v1b0 >= 1.f) ? 1.f : 0.f; v1b0 -= s0;
        spk[ch1][r1 + 1][c1 + 1] = s0;
        v1a1 = ALPHA * v1a1 + xt1; v1b1 = ALPHA * v1b1 + v1a1;
        float s1 = (v1b1 >= 1.f) ? 1.f : 0.f; v1b1 -= s1;
        spk[ch1 + 2][r1 + 1][c1 + 1] = s1;
        xt0 = xn0; xt1 = xn1;
        __syncthreads();

        // conv2 (4 partial accumulators -> short dependency chains)
        float p0 = 0.f, p1 = 0.f, p2 = 0.f, p3 = 0.f;
        C2(0, 0, w00, p0) C2(0, 1, w01, p0) C2(0, 2, w02, p0) C2(0, 3, w03, p0)
        C2(1, 0, w04, p1) C2(1, 1, w05, p1) C2(1, 2, w06, p1) C2(1, 3, w07, p1)
        C2(2, 0, w08, p2) C2(2, 1, w09, p2) C2(2, 2, w10, p2) C2(2, 3, w11, p2)
        C2(3, 0, w12, p3) C2(3, 1, w13, p3) C2(3, 2, w14, p3) C2(3, 3, w15, p3)
        float acc = (p0 + p1) + (p2 + p3);

        // stage-2 exp_leak + LIF
        v2a = ALPHA * v2a + acc; v2b = ALPHA * v2b + v2a;
        float ss = (v2b >= 1.f) ? 1.f : 0.f; v2b -= ss;
        s2all[t][tid] = ss;
        __syncthreads();
    }
#undef C2

    // epilogue: out[t][o] = sum_f s2all[t][f] * lw[o][f];  thread -> t
    if (tid < 100) {
        const float4* sa  = (const float4*)&s2all[tid][0];
        const float4* lw4 = (const float4*)lwl;
        float e0a = 0.f, e0b = 0.f, e1a = 0.f, e1b = 0.f;
        #pragma unroll
        for (int k = 0; k < 32; k += 2) {
            float4 A = sa[k], B = sa[k + 1];
            float4 u0 = lw4[k], u1 = lw4[k + 1];
            float4 v0 = lw4[32 + k], v1 = lw4[33 + k];
            e0a += A.x * u0.x + A.y * u0.y + A.z * u0.z + A.w * u0.w;
            e0b += B.x * u1.x + B.y * u1.y + B.z * u1.z + B.w * u1.w;
            e1a += A.x * v0.x + A.y * v0.y + A.z * v0.z + A.w * v0.w;
            e1b += B.x * v1.x + B.y * v1.y + B.z * v1.z + B.w * v1.w;
        }
        float2 res = make_float2(e0a + e0b, e1a + e1b);
        *(float2*)(out + (long)b * 200 + tid * 2) = res;
    }
}

extern "C" void kernel_launch(void* const* d_in, const int* in_sizes, int n_in,
                              void* d_out, int out_size, void* d_ws, size_t ws_size,
                              hipStream_t stream) {
    const float* x  = (const float*)d_in[0];   // [128,100,2,32,32]
    const float* w1 = (const float*)d_in[1];   // [4,2,5,5]
    const float* w2 = (const float*)d_in[2];   // [8,4,3,3]
    const float* lw = (const float*)d_in[3];   // [2,128]
    float* out = (float*)d_out;                // [128,100,2]

    float* ws  = (float*)d_ws;
    float* w1e = ws;                 // 512 floats
    float* w2e = ws + 512;           // 512 floats
    float* y1  = ws + 1024;          // 12800*256 floats = 13.1 MB

    prep_weights<<<4, 256, 0, stream>>>(w1, w2, w1e, w2e);
    conv1_pool<<<3200, 256, 0, stream>>>(x, w1e, y1);
    fused_rest<<<128, 128, 0, stream>>>(y1, w2e, lw, out);
}